// Round 1
// baseline (210.522 us; speedup 1.0000x reference)
//
#include <hip/hip_runtime.h>
#include <hip/hip_bf16.h>

// Problem: B=8, N=1024, DQ=DK=DV=256, H=8, head_dim=32.
// Pipeline (all bf16 MFMA, fp32 accum):
//   K0 wtrans : W[k][n] f32 -> WT[n][k] bf16 (so MFMA B-frags are contiguous)
//   K1 proj   : q=(Q@Wq+bq)*mask, k=(K@Wk+bk)*mask, v=(K@Wv+bv)*mask
//               q,k stored [b][h][n][32] bf16 ; v stored transposed [b][h][32][n]
//   K2 attn   : per (b,h,64 q-rows): S=q k^T/16, e=exp(S)*colmask, O=q+ (e@v)/(rowsum+1e-15),
//               rowmask applied; flash-style, no max subtraction (scores are small)
//   K3 ln0    : LayerNorm(g0,b0) -> Xb bf16
//   K4 out    : Y = X + relu(X@Wo+bo); out = LayerNorm(Y,g1,b1)  (fused epilogue)

#define NTOK 8192

typedef __attribute__((ext_vector_type(8))) short short8;
typedef __attribute__((ext_vector_type(4))) short short4v;
typedef __attribute__((ext_vector_type(4))) float f32x4;

__device__ __forceinline__ short f2bf(float f) {
    union { float f; unsigned u; } x; x.f = f;
    unsigned r = x.u + 0x7fffu + ((x.u >> 16) & 1u);   // RNE
    return (short)(r >> 16);
}
__device__ __forceinline__ float bf2f(short s) {
    union { unsigned u; float f; } x; x.u = ((unsigned)(unsigned short)s) << 16;
    return x.f;
}

// ---------------- K0: transpose + convert weights ----------------
__global__ __launch_bounds__(256) void wtrans_kernel(
    const float* __restrict__ Wq, const float* __restrict__ Wk,
    const float* __restrict__ Wv, const float* __restrict__ Wo,
    short* __restrict__ WqT, short* __restrict__ WkT,
    short* __restrict__ WvT, short* __restrict__ WoT)
{
    const float* W; short* T;
    switch (blockIdx.y) {
        case 0:  W = Wq; T = WqT; break;
        case 1:  W = Wk; T = WkT; break;
        case 2:  W = Wv; T = WvT; break;
        default: W = Wo; T = WoT; break;
    }
    int base = blockIdx.x * 4096 + threadIdx.x;
    #pragma unroll
    for (int i = 0; i < 16; i++) {
        int e = base + i * 256;        // e = n*256 + k
        int n = e >> 8, k = e & 255;
        T[e] = f2bf(W[k * 256 + n]);
    }
}

// ---------------- K1: q/k/v projections ----------------
// grid (128, 3) blocks of 256. Each block: 64 token rows x 256 cols. Wave: 16 rows.
__global__ __launch_bounds__(256) void proj_kernel(
    const float* __restrict__ Q, const float* __restrict__ Kin,
    const short* __restrict__ WqT, const short* __restrict__ WkT, const short* __restrict__ WvT,
    const float* __restrict__ bq, const float* __restrict__ bk, const float* __restrict__ bv,
    const int* __restrict__ lengths,
    short* __restrict__ qb, short* __restrict__ kb, short* __restrict__ vT)
{
    const int which = blockIdx.y;                 // 0=q,1=k,2=v
    const float* A    = (which == 0) ? Q   : Kin;
    const short* WT   = (which == 0) ? WqT : (which == 1) ? WkT : WvT;
    const float* bias = (which == 0) ? bq  : (which == 1) ? bk  : bv;

    const int tid = threadIdx.x;
    const int lane = tid & 63, wid = tid >> 6;
    const int m = lane & 15, quad = lane >> 4;
    const int r0 = blockIdx.x * 64 + wid * 16;    // wave's token row base
    const int b = (blockIdx.x * 64) >> 10;        // batch (tiles never cross batches)
    const int len = lengths[b];

    f32x4 acc[16];
    #pragma unroll
    for (int t = 0; t < 16; t++) acc[t] = (f32x4){0.f, 0.f, 0.f, 0.f};

    const float* arow = A + (size_t)(r0 + m) * 256;
    for (int kk = 0; kk < 256; kk += 32) {
        const float* ap = arow + kk + quad * 8;
        float4 f0 = *(const float4*)(ap);
        float4 f1 = *(const float4*)(ap + 4);
        short8 af;
        af[0] = f2bf(f0.x); af[1] = f2bf(f0.y); af[2] = f2bf(f0.z); af[3] = f2bf(f0.w);
        af[4] = f2bf(f1.x); af[5] = f2bf(f1.y); af[6] = f2bf(f1.z); af[7] = f2bf(f1.w);
        #pragma unroll
        for (int t = 0; t < 16; t++) {
            short8 bf = *(const short8*)(WT + (t * 16 + m) * 256 + kk + quad * 8);
            acc[t] = __builtin_amdgcn_mfma_f32_16x16x32_bf16(af, bf, acc[t], 0, 0, 0);
        }
    }

    #pragma unroll
    for (int t = 0; t < 16; t++) {
        int n = t * 16 + m;                        // output column
        float bv_ = bias[n];
        int h = n >> 5, i = n & 31;
        int bh = b * 8 + h;
        #pragma unroll
        for (int reg = 0; reg < 4; reg++) {
            int token = r0 + quad * 4 + reg;       // C layout: row = quad*4+reg
            int ntok = token & 1023;
            float val = (ntok < len) ? (acc[t][reg] + bv_) : 0.f;
            short s = f2bf(val);
            if (which == 2) {
                vT[(size_t)(bh * 32 + i) * 1024 + ntok] = s;
            } else {
                short* dst = (which == 0) ? qb : kb;
                dst[((size_t)bh * 1024 + ntok) * 32 + i] = s;
            }
        }
    }
}

// ---------------- K2: attention ----------------
// grid (16, 64): x = q-tile (64 rows), y = b*8+h. Block 256 = 4 waves x 16 q-rows.
__global__ __launch_bounds__(256) void attn_kernel(
    const short* __restrict__ qb, const short* __restrict__ kb, const short* __restrict__ vT,
    const int* __restrict__ lengths, float* __restrict__ O1)
{
    __shared__ short P[4][16][64];                 // per-wave P tile (q-rows x keys), bf16
    const int tid = threadIdx.x;
    const int lane = tid & 63, wid = tid >> 6;
    const int m = lane & 15, quad = lane >> 4;
    const int bh = blockIdx.y;
    const int b = bh >> 3, h = bh & 7;
    const int len = lengths[b];
    const int qr0 = blockIdx.x * 64 + wid * 16;

    const short* qbase = qb + (size_t)bh * 1024 * 32;
    const short* kbase = kb + (size_t)bh * 1024 * 32;
    const short* vbase = vT + (size_t)bh * 32 * 1024;

    // A-frag of q: rows qr0..qr0+15, k-dim 32 == one MFMA K step. Load once.
    const short8 qf = *(const short8*)(qbase + (qr0 + m) * 32 + quad * 8);

    f32x4 o0 = (f32x4){0.f, 0.f, 0.f, 0.f};       // vdims 0..15
    f32x4 o1 = (f32x4){0.f, 0.f, 0.f, 0.f};       // vdims 16..31
    float l[4] = {0.f, 0.f, 0.f, 0.f};            // rowsum partials (row = quad*4+reg)

    for (int key0 = 0; key0 < 1024; key0 += 64) {
        #pragma unroll
        for (int t = 0; t < 4; t++) {
            short8 kf = *(const short8*)(kbase + (key0 + t * 16 + m) * 32 + quad * 8);
            f32x4 s = __builtin_amdgcn_mfma_f32_16x16x32_bf16(qf, kf,
                        (f32x4){0.f, 0.f, 0.f, 0.f}, 0, 0, 0);
            int col = key0 + t * 16 + m;           // key index (C layout col)
            bool cm = col < len;
            #pragma unroll
            for (int reg = 0; reg < 4; reg++) {
                float e = cm ? __expf(s[reg] * 0.0625f) : 0.f;   // /sqrt(256)
                l[reg] += e;
                P[wid][quad * 4 + reg][t * 16 + m] = f2bf(e);
            }
        }
        __syncthreads();                            // P write -> P read
        #pragma unroll
        for (int c = 0; c < 2; c++) {
            short8 pf  = *(const short8*)(&P[wid][m][c * 32 + quad * 8]);
            short8 vf0 = *(const short8*)(vbase + (size_t)(m) * 1024      + key0 + c * 32 + quad * 8);
            short8 vf1 = *(const short8*)(vbase + (size_t)(16 + m) * 1024 + key0 + c * 32 + quad * 8);
            o0 = __builtin_amdgcn_mfma_f32_16x16x32_bf16(pf, vf0, o0, 0, 0, 0);
            o1 = __builtin_amdgcn_mfma_f32_16x16x32_bf16(pf, vf1, o1, 0, 0, 0);
        }
        __syncthreads();
    }

    // reduce rowsums across the 16 lanes of each quad group
    #pragma unroll
    for (int reg = 0; reg < 4; reg++) {
        float s = l[reg];
        s += __shfl_xor(s, 1); s += __shfl_xor(s, 2);
        s += __shfl_xor(s, 4); s += __shfl_xor(s, 8);
        l[reg] = s;
    }

    const int hbase = h * 32;
    #pragma unroll
    for (int reg = 0; reg < 4; reg++) {
        int r = quad * 4 + reg;
        int qrow = qr0 + r;                        // within-batch row
        float f = (qrow < len) ? 1.f / (l[reg] + 1e-15f) : 0.f;
        size_t obase = ((size_t)(b * 1024 + qrow)) * 256 + hbase;
        float q0 = bf2f(qbase[(qrow) * 32 + m]);
        float q1 = bf2f(qbase[(qrow) * 32 + 16 + m]);
        O1[obase + m]      = q0 + o0[reg] * f;
        O1[obase + 16 + m] = q1 + o1[reg] * f;
    }
}

// ---------------- K3: LayerNorm 0 ----------------
// one wave per token, 4 cols/lane
__global__ __launch_bounds__(256) void ln0_kernel(
    const float* __restrict__ O1, const float* __restrict__ g0, const float* __restrict__ b0,
    short* __restrict__ Xb)
{
    const int tid = threadIdx.x;
    const int lane = tid & 63, wid = tid >> 6;
    const int token = blockIdx.x * 4 + wid;
    const float* row = O1 + (size_t)token * 256;
    float4 x = *(const float4*)(row + lane * 4);
    float s  = x.x + x.y + x.z + x.w;
    float s2 = x.x * x.x + x.y * x.y + x.z * x.z + x.w * x.w;
    #pragma unroll
    for (int msk = 1; msk < 64; msk <<= 1) {
        s  += __shfl_xor(s, msk);
        s2 += __shfl_xor(s2, msk);
    }
    float mean = s * (1.f / 256.f);
    float var  = s2 * (1.f / 256.f) - mean * mean;
    float rs = rsqrtf(var + 1e-5f);
    float4 g = *(const float4*)(g0 + lane * 4);
    float4 bb = *(const float4*)(b0 + lane * 4);
    short4v y;
    y[0] = f2bf((x.x - mean) * rs * g.x + bb.x);
    y[1] = f2bf((x.y - mean) * rs * g.y + bb.y);
    y[2] = f2bf((x.z - mean) * rs * g.z + bb.z);
    y[3] = f2bf((x.w - mean) * rs * g.w + bb.w);
    *(short4v*)(Xb + (size_t)token * 256 + lane * 4) = y;
}

// ---------------- K4: output projection + relu residual + LayerNorm 1 ----------------
// grid 128 blocks of 256. Block: 64 rows x 256 cols (full rows -> LN1 fused).
__global__ __launch_bounds__(256) void out_kernel(
    const short* __restrict__ Xb, const short* __restrict__ WoT,
    const float* __restrict__ bo, const float* __restrict__ g1, const float* __restrict__ b1,
    float* __restrict__ out)
{
    const int tid = threadIdx.x;
    const int lane = tid & 63, wid = tid >> 6;
    const int m = lane & 15, quad = lane >> 4;
    const int r0 = blockIdx.x * 64 + wid * 16;

    f32x4 acc[16];
    #pragma unroll
    for (int t = 0; t < 16; t++) acc[t] = (f32x4){0.f, 0.f, 0.f, 0.f};

    const short* arow = Xb + (size_t)(r0 + m) * 256;
    for (int kk = 0; kk < 256; kk += 32) {
        short8 af = *(const short8*)(arow + kk + quad * 8);
        #pragma unroll
        for (int t = 0; t < 16; t++) {
            short8 bf = *(const short8*)(WoT + (t * 16 + m) * 256 + kk + quad * 8);
            acc[t] = __builtin_amdgcn_mfma_f32_16x16x32_bf16(af, bf, acc[t], 0, 0, 0);
        }
    }

    // epilogue: y = x + relu(c + bo); row stats; LN1
    float s1[4] = {0.f, 0.f, 0.f, 0.f};
    float s2[4] = {0.f, 0.f, 0.f, 0.f};
    #pragma unroll
    for (int t = 0; t < 16; t++) {
        int n = t * 16 + m;
        float bon = bo[n];
        #pragma unroll
        for (int reg = 0; reg < 4; reg++) {
            int token = r0 + quad * 4 + reg;
            float xv = bf2f(Xb[(size_t)token * 256 + n]);
            float c = acc[t][reg] + bon;
            float yv = xv + (c > 0.f ? c : 0.f);
            acc[t][reg] = yv;                       // reuse acc as y storage
            s1[reg] += yv;
            s2[reg] += yv * yv;
        }
    }
    #pragma unroll
    for (int reg = 0; reg < 4; reg++) {
        float a = s1[reg], bq_ = s2[reg];
        a += __shfl_xor(a, 1); a += __shfl_xor(a, 2); a += __shfl_xor(a, 4); a += __shfl_xor(a, 8);
        bq_ += __shfl_xor(bq_, 1); bq_ += __shfl_xor(bq_, 2); bq_ += __shfl_xor(bq_, 4); bq_ += __shfl_xor(bq_, 8);
        s1[reg] = a; s2[reg] = bq_;
    }
    #pragma unroll
    for (int reg = 0; reg < 4; reg++) {
        float mean = s1[reg] * (1.f / 256.f);
        float var  = s2[reg] * (1.f / 256.f) - mean * mean;
        float rs = rsqrtf(var + 1e-5f);
        int token = r0 + quad * 4 + reg;
        #pragma unroll
        for (int t = 0; t < 16; t++) {
            int n = t * 16 + m;
            out[(size_t)token * 256 + n] = (acc[t][reg] - mean) * rs * g1[n] + b1[n];
        }
    }
}

extern "C" void kernel_launch(void* const* d_in, const int* in_sizes, int n_in,
                              void* d_out, int out_size, void* d_ws, size_t ws_size,
                              hipStream_t stream) {
    const float* Q   = (const float*)d_in[0];
    const float* K   = (const float*)d_in[1];
    const int* lengths = (const int*)d_in[2];
    const float* Wq  = (const float*)d_in[3];
    const float* bq  = (const float*)d_in[4];
    const float* Wk  = (const float*)d_in[5];
    const float* bk  = (const float*)d_in[6];
    const float* Wv  = (const float*)d_in[7];
    const float* bv  = (const float*)d_in[8];
    const float* Wo  = (const float*)d_in[9];
    const float* bo  = (const float*)d_in[10];
    const float* g0  = (const float*)d_in[11];
    const float* b0  = (const float*)d_in[12];
    const float* g1  = (const float*)d_in[13];
    const float* b1  = (const float*)d_in[14];
    float* out = (float*)d_out;

    char* ws = (char*)d_ws;
    short* qb  = (short*)(ws);                         // [8][8][1024][32] bf16, 4 MB
    short* kb  = (short*)(ws + (4u << 20));            // 4 MB
    short* vT  = (short*)(ws + (8u << 20));            // [8][8][32][1024] bf16, 4 MB
    float* O1  = (float*)(ws + (12u << 20));           // [8192][256] f32, 8 MB
    short* Xb  = (short*)(ws + (20u << 20));           // [8192][256] bf16, 4 MB
    short* WqT = (short*)(ws + (24u << 20));           // 128 KB each, [n][k] bf16
    short* WkT = (short*)(ws + (24u << 20) + (128u << 10));
    short* WvT = (short*)(ws + (24u << 20) + (256u << 10));
    short* WoT = (short*)(ws + (24u << 20) + (384u << 10));

    wtrans_kernel<<<dim3(16, 4), 256, 0, stream>>>(Wq, Wk, Wv, Wo, WqT, WkT, WvT, WoT);
    proj_kernel<<<dim3(128, 3), 256, 0, stream>>>(Q, K, WqT, WkT, WvT, bq, bk, bv,
                                                  lengths, qb, kb, vT);
    attn_kernel<<<dim3(16, 64), 256, 0, stream>>>(qb, kb, vT, lengths, O1);
    ln0_kernel<<<dim3(2048), 256, 0, stream>>>(O1, g0, b0, Xb);
    out_kernel<<<dim3(128), 256, 0, stream>>>(Xb, WoT, bo, g1, b1, out);
}

// Round 2
// 166.151 us; speedup vs baseline: 1.2671x; 1.2671x over previous
//
#include <hip/hip_runtime.h>
#include <hip/hip_bf16.h>

// Problem: B=8, N=1024, DQ=DK=DV=256, H=8, head_dim=32.
// Pipeline (all bf16 MFMA, fp32 accum):
//   K0 wtrans : W[k][n] f32 -> WT[n][k] bf16
//   K1 proj   : q=(Q@Wq+bq)*mask, k=(K@Wk+bk)*mask, v=(K@Wv+bv)*mask
//               q,k stored [b][h][n][32] bf16 ; v stored transposed [b][h][32][n]
//   K2 attn   : split-K flash-style, no max subtraction; key loop bounded by len;
//               wave-private P tile (no block barriers in the loop), padded stride
//   K3 ln0    : LayerNorm(g0,b0) -> Xb bf16
//   K4 out    : Y = X + relu(X@Wo+bo); out = LayerNorm(Y,g1,b1) (cross-wave stats via LDS)

typedef __attribute__((ext_vector_type(8))) short short8;
typedef __attribute__((ext_vector_type(4))) short short4v;
typedef __attribute__((ext_vector_type(4))) float f32x4;

__device__ __forceinline__ short f2bf(float f) {
    union { float f; unsigned u; } x; x.f = f;
    unsigned r = x.u + 0x7fffu + ((x.u >> 16) & 1u);   // RNE
    return (short)(r >> 16);
}
__device__ __forceinline__ float bf2f(short s) {
    union { unsigned u; float f; } x; x.u = ((unsigned)(unsigned short)s) << 16;
    return x.f;
}

// ---------------- K0: transpose + convert weights ----------------
__global__ __launch_bounds__(256) void wtrans_kernel(
    const float* __restrict__ Wq, const float* __restrict__ Wk,
    const float* __restrict__ Wv, const float* __restrict__ Wo,
    short* __restrict__ WqT, short* __restrict__ WkT,
    short* __restrict__ WvT, short* __restrict__ WoT)
{
    const float* W; short* T;
    switch (blockIdx.y) {
        case 0:  W = Wq; T = WqT; break;
        case 1:  W = Wk; T = WkT; break;
        case 2:  W = Wv; T = WvT; break;
        default: W = Wo; T = WoT; break;
    }
    int base = blockIdx.x * 4096 + threadIdx.x;
    #pragma unroll
    for (int i = 0; i < 16; i++) {
        int e = base + i * 256;        // e = n*256 + k
        int n = e >> 8, k = e & 255;
        T[e] = f2bf(W[k * 256 + n]);
    }
}

// ---------------- K1: q/k/v projections ----------------
// grid (256, 3) blocks of 256. Block: 32 token rows x 256 cols.
// Wave: 16 rows x 128 cols (rh = wid>>1 row-half, ch = wid&1 col-half).
__global__ __launch_bounds__(256) void proj_kernel(
    const float* __restrict__ Q, const float* __restrict__ Kin,
    const short* __restrict__ WqT, const short* __restrict__ WkT, const short* __restrict__ WvT,
    const float* __restrict__ bq, const float* __restrict__ bk, const float* __restrict__ bv,
    const int* __restrict__ lengths,
    short* __restrict__ qb, short* __restrict__ kb, short* __restrict__ vT)
{
    const int which = blockIdx.y;                 // 0=q,1=k,2=v
    const float* A    = (which == 0) ? Q   : Kin;
    const short* WT   = (which == 0) ? WqT : (which == 1) ? WkT : WvT;
    const float* bias = (which == 0) ? bq  : (which == 1) ? bk  : bv;

    const int tid = threadIdx.x;
    const int lane = tid & 63, wid = tid >> 6;
    const int m = lane & 15, quad = lane >> 4;
    const int rh = wid >> 1, ch = wid & 1;
    const int r0 = blockIdx.x * 32 + rh * 16;     // wave's token row base (global)
    const int c0 = ch * 128;                      // wave's column base
    const int b = blockIdx.x >> 5;                // batch (32 rows/block, 32 blocks/batch)
    const int len = lengths[b];
    const int ntok0 = r0 & 1023;                  // within-batch row base

    f32x4 acc[8];
    #pragma unroll
    for (int t = 0; t < 8; t++) acc[t] = (f32x4){0.f, 0.f, 0.f, 0.f};

    if (ntok0 < len) {                            // fully-masked tiles: skip GEMM
        const float* arow = A + (size_t)(r0 + m) * 256;
        for (int kk = 0; kk < 256; kk += 32) {
            const float* ap = arow + kk + quad * 8;
            float4 f0 = *(const float4*)(ap);
            float4 f1 = *(const float4*)(ap + 4);
            short8 af;
            af[0] = f2bf(f0.x); af[1] = f2bf(f0.y); af[2] = f2bf(f0.z); af[3] = f2bf(f0.w);
            af[4] = f2bf(f1.x); af[5] = f2bf(f1.y); af[6] = f2bf(f1.z); af[7] = f2bf(f1.w);
            #pragma unroll
            for (int t = 0; t < 8; t++) {
                short8 bf = *(const short8*)(WT + (c0 + t * 16 + m) * 256 + kk + quad * 8);
                acc[t] = __builtin_amdgcn_mfma_f32_16x16x32_bf16(af, bf, acc[t], 0, 0, 0);
            }
        }
    }

    #pragma unroll
    for (int t = 0; t < 8; t++) {
        int n = c0 + t * 16 + m;                   // output column
        float bv_ = bias[n];
        int h = n >> 5, i = n & 31;
        int bh = b * 8 + h;
        #pragma unroll
        for (int reg = 0; reg < 4; reg++) {
            int ntok = ntok0 + quad * 4 + reg;     // C layout: row = quad*4+reg
            float val = (ntok < len) ? (acc[t][reg] + bv_) : 0.f;
            short s = f2bf(val);
            if (which == 2) {
                vT[(size_t)(bh * 32 + i) * 1024 + ntok] = s;
            } else {
                short* dst = (which == 0) ? qb : kb;
                dst[((size_t)bh * 1024 + ntok) * 32 + i] = s;
            }
        }
    }
}

// ---------------- K2: attention ----------------
// grid (32, 64): x = q-tile (32 rows), y = b*8+h. Block 256 = 4 waves.
// Wave (qh, ks): q-rows [qr0, qr0+16), keys [ks*512, ks*512+512) bounded by len.
// No barriers in the key loop (P is wave-private); one barrier for split-K combine.
__global__ __launch_bounds__(256) void attn_kernel(
    const short* __restrict__ qb, const short* __restrict__ kb, const short* __restrict__ vT,
    const int* __restrict__ lengths, float* __restrict__ O1)
{
    __shared__ short P[4][16][72];                 // per-wave P tile, padded (72 shorts/row)
    __shared__ float cbO[2][16][33];               // split-K partial O from ks=1 waves
    __shared__ float cbL[2][16];                   // split-K partial rowsums
    const int tid = threadIdx.x;
    const int lane = tid & 63, wid = tid >> 6;
    const int m = lane & 15, quad = lane >> 4;
    const int ks = wid & 1, qh = wid >> 1;
    const int bh = blockIdx.y;
    const int b = bh >> 3, h = bh & 7;
    const int len = lengths[b];
    const int qr0 = blockIdx.x * 32 + qh * 16;

    const short* qbase = qb + (size_t)bh * 1024 * 32;
    const short* kbase = kb + (size_t)bh * 1024 * 32;
    const short* vbase = vT + (size_t)bh * 32 * 1024;

    // A-frag of q: rows qr0..qr0+15, k-dim 32 == one MFMA K step. Load once.
    const short8 qf = *(const short8*)(qbase + (qr0 + m) * 32 + quad * 8);

    f32x4 o0 = (f32x4){0.f, 0.f, 0.f, 0.f};       // vdims 0..15
    f32x4 o1 = (f32x4){0.f, 0.f, 0.f, 0.f};       // vdims 16..31
    float l[4] = {0.f, 0.f, 0.f, 0.f};            // rowsum partials (row = quad*4+reg)

    const int kbeg = ks * 512;
    int kchunks = 0;
    if (qr0 < len && len > kbeg) {
        int rem = len - kbeg;
        kchunks = rem >= 512 ? 8 : ((rem + 63) >> 6);
    }

    for (int ci = 0; ci < kchunks; ci++) {
        int key0 = kbeg + ci * 64;
        #pragma unroll
        for (int t = 0; t < 4; t++) {
            short8 kf = *(const short8*)(kbase + (key0 + t * 16 + m) * 32 + quad * 8);
            f32x4 s = __builtin_amdgcn_mfma_f32_16x16x32_bf16(qf, kf,
                        (f32x4){0.f, 0.f, 0.f, 0.f}, 0, 0, 0);
            int col = key0 + t * 16 + m;           // key index (C layout col)
            bool cm = col < len;
            #pragma unroll
            for (int reg = 0; reg < 4; reg++) {
                float e = cm ? __expf(s[reg] * 0.0625f) : 0.f;   // /sqrt(256)
                l[reg] += e;
                P[wid][quad * 4 + reg][t * 16 + m] = f2bf(e);
            }
        }
        // wave-private tile: per-wave LDS ordering only, no block barrier
        asm volatile("s_waitcnt lgkmcnt(0)" ::: "memory");
        #pragma unroll
        for (int c = 0; c < 2; c++) {
            short8 pf  = *(const short8*)(&P[wid][m][c * 32 + quad * 8]);
            short8 vf0 = *(const short8*)(vbase + (size_t)(m) * 1024      + key0 + c * 32 + quad * 8);
            short8 vf1 = *(const short8*)(vbase + (size_t)(16 + m) * 1024 + key0 + c * 32 + quad * 8);
            o0 = __builtin_amdgcn_mfma_f32_16x16x32_bf16(pf, vf0, o0, 0, 0, 0);
            o1 = __builtin_amdgcn_mfma_f32_16x16x32_bf16(pf, vf1, o1, 0, 0, 0);
        }
    }

    // reduce rowsums across the 16 lanes of each quad group
    #pragma unroll
    for (int reg = 0; reg < 4; reg++) {
        float s = l[reg];
        s += __shfl_xor(s, 1); s += __shfl_xor(s, 2);
        s += __shfl_xor(s, 4); s += __shfl_xor(s, 8);
        l[reg] = s;
    }

    // split-K combine: ks=1 publishes partials, ks=0 merges + writes out
    if (ks == 1) {
        #pragma unroll
        for (int reg = 0; reg < 4; reg++) {
            cbO[qh][quad * 4 + reg][m]      = o0[reg];
            cbO[qh][quad * 4 + reg][16 + m] = o1[reg];
        }
        if (m == 0) {
            #pragma unroll
            for (int reg = 0; reg < 4; reg++) cbL[qh][quad * 4 + reg] = l[reg];
        }
    }
    __syncthreads();
    if (ks == 0) {
        const int hbase = h * 32;
        #pragma unroll
        for (int reg = 0; reg < 4; reg++) {
            int r = quad * 4 + reg;
            o0[reg] += cbO[qh][r][m];
            o1[reg] += cbO[qh][r][16 + m];
            float lt = l[reg] + cbL[qh][r];
            int qrow = qr0 + r;                    // within-batch row
            float f = (qrow < len) ? 1.f / (lt + 1e-15f) : 0.f;
            size_t obase = ((size_t)(b * 1024 + qrow)) * 256 + hbase;
            float q0 = bf2f(qbase[qrow * 32 + m]);
            float q1 = bf2f(qbase[qrow * 32 + 16 + m]);
            O1[obase + m]      = q0 + o0[reg] * f;
            O1[obase + 16 + m] = q1 + o1[reg] * f;
        }
    }
}

// ---------------- K3: LayerNorm 0 ----------------
// one wave per token, 4 cols/lane
__global__ __launch_bounds__(256) void ln0_kernel(
    const float* __restrict__ O1, const float* __restrict__ g0, const float* __restrict__ b0,
    short* __restrict__ Xb)
{
    const int tid = threadIdx.x;
    const int lane = tid & 63, wid = tid >> 6;
    const int token = blockIdx.x * 4 + wid;
    const float* row = O1 + (size_t)token * 256;
    float4 x = *(const float4*)(row + lane * 4);
    float s  = x.x + x.y + x.z + x.w;
    float s2 = x.x * x.x + x.y * x.y + x.z * x.z + x.w * x.w;
    #pragma unroll
    for (int msk = 1; msk < 64; msk <<= 1) {
        s  += __shfl_xor(s, msk);
        s2 += __shfl_xor(s2, msk);
    }
    float mean = s * (1.f / 256.f);
    float var  = s2 * (1.f / 256.f) - mean * mean;
    float rs = rsqrtf(var + 1e-5f);
    float4 g = *(const float4*)(g0 + lane * 4);
    float4 bb = *(const float4*)(b0 + lane * 4);
    short4v y;
    y[0] = f2bf((x.x - mean) * rs * g.x + bb.x);
    y[1] = f2bf((x.y - mean) * rs * g.y + bb.y);
    y[2] = f2bf((x.z - mean) * rs * g.z + bb.z);
    y[3] = f2bf((x.w - mean) * rs * g.w + bb.w);
    *(short4v*)(Xb + (size_t)token * 256 + lane * 4) = y;
}

// ---------------- K4: output projection + relu residual + LayerNorm 1 ----------------
// grid 256 blocks of 256. Block: 32 rows; wave = 16 rows x 128 cols.
// LN1 row stats exchanged across the two col-half waves via LDS.
__global__ __launch_bounds__(256) void out_kernel(
    const short* __restrict__ Xb, const short* __restrict__ WoT,
    const float* __restrict__ bo, const float* __restrict__ g1, const float* __restrict__ b1,
    float* __restrict__ out)
{
    __shared__ float st[2][2][2][16];              // [rowhalf][colhalf][{s1,s2}][row]
    const int tid = threadIdx.x;
    const int lane = tid & 63, wid = tid >> 6;
    const int m = lane & 15, quad = lane >> 4;
    const int rh = wid >> 1, ch = wid & 1;
    const int r0 = blockIdx.x * 32 + rh * 16;
    const int c0 = ch * 128;

    f32x4 acc[8];
    #pragma unroll
    for (int t = 0; t < 8; t++) acc[t] = (f32x4){0.f, 0.f, 0.f, 0.f};

    const short* arow = Xb + (size_t)(r0 + m) * 256;
    for (int kk = 0; kk < 256; kk += 32) {
        short8 af = *(const short8*)(arow + kk + quad * 8);
        #pragma unroll
        for (int t = 0; t < 8; t++) {
            short8 bf = *(const short8*)(WoT + (c0 + t * 16 + m) * 256 + kk + quad * 8);
            acc[t] = __builtin_amdgcn_mfma_f32_16x16x32_bf16(af, bf, acc[t], 0, 0, 0);
        }
    }

    // epilogue: y = x + relu(c + bo); partial row stats over this col-half
    float s1[4] = {0.f, 0.f, 0.f, 0.f};
    float s2[4] = {0.f, 0.f, 0.f, 0.f};
    #pragma unroll
    for (int t = 0; t < 8; t++) {
        int n = c0 + t * 16 + m;
        float bon = bo[n];
        #pragma unroll
        for (int reg = 0; reg < 4; reg++) {
            int token = r0 + quad * 4 + reg;
            float xv = bf2f(Xb[(size_t)token * 256 + n]);
            float c = acc[t][reg] + bon;
            float yv = xv + (c > 0.f ? c : 0.f);
            acc[t][reg] = yv;                       // reuse acc as y storage
            s1[reg] += yv;
            s2[reg] += yv * yv;
        }
    }
    #pragma unroll
    for (int reg = 0; reg < 4; reg++) {
        float a = s1[reg], bsum = s2[reg];
        a += __shfl_xor(a, 1); a += __shfl_xor(a, 2); a += __shfl_xor(a, 4); a += __shfl_xor(a, 8);
        bsum += __shfl_xor(bsum, 1); bsum += __shfl_xor(bsum, 2); bsum += __shfl_xor(bsum, 4); bsum += __shfl_xor(bsum, 8);
        s1[reg] = a; s2[reg] = bsum;
    }
    if (m == 0) {
        #pragma unroll
        for (int reg = 0; reg < 4; reg++) {
            st[rh][ch][0][quad * 4 + reg] = s1[reg];
            st[rh][ch][1][quad * 4 + reg] = s2[reg];
        }
    }
    __syncthreads();
    #pragma unroll
    for (int reg = 0; reg < 4; reg++) {
        int r = quad * 4 + reg;
        float t1 = s1[reg] + st[rh][ch ^ 1][0][r];
        float t2 = s2[reg] + st[rh][ch ^ 1][1][r];
        float mean = t1 * (1.f / 256.f);
        float var  = t2 * (1.f / 256.f) - mean * mean;
        float rs = rsqrtf(var + 1e-5f);
        int token = r0 + r;
        #pragma unroll
        for (int t = 0; t < 8; t++) {
            int n = c0 + t * 16 + m;
            out[(size_t)token * 256 + n] = (acc[t][reg] - mean) * rs * g1[n] + b1[n];
        }
    }
}

extern "C" void kernel_launch(void* const* d_in, const int* in_sizes, int n_in,
                              void* d_out, int out_size, void* d_ws, size_t ws_size,
                              hipStream_t stream) {
    const float* Q   = (const float*)d_in[0];
    const float* K   = (const float*)d_in[1];
    const int* lengths = (const int*)d_in[2];
    const float* Wq  = (const float*)d_in[3];
    const float* bq  = (const float*)d_in[4];
    const float* Wk  = (const float*)d_in[5];
    const float* bk  = (const float*)d_in[6];
    const float* Wv  = (const float*)d_in[7];
    const float* bv  = (const float*)d_in[8];
    const float* Wo  = (const float*)d_in[9];
    const float* bo  = (const float*)d_in[10];
    const float* g0  = (const float*)d_in[11];
    const float* b0  = (const float*)d_in[12];
    const float* g1  = (const float*)d_in[13];
    const float* b1  = (const float*)d_in[14];
    float* out = (float*)d_out;

    char* ws = (char*)d_ws;
    short* qb  = (short*)(ws);                         // [8][8][1024][32] bf16, 4 MB
    short* kb  = (short*)(ws + (4u << 20));            // 4 MB
    short* vT  = (short*)(ws + (8u << 20));            // [8][8][32][1024] bf16, 4 MB
    float* O1  = (float*)(ws + (12u << 20));           // [8192][256] f32, 8 MB
    short* Xb  = (short*)(ws + (20u << 20));           // [8192][256] bf16, 4 MB
    short* WqT = (short*)(ws + (24u << 20));           // 128 KB each, [n][k] bf16
    short* WkT = (short*)(ws + (24u << 20) + (128u << 10));
    short* WvT = (short*)(ws + (24u << 20) + (256u << 10));
    short* WoT = (short*)(ws + (24u << 20) + (384u << 10));

    wtrans_kernel<<<dim3(16, 4), 256, 0, stream>>>(Wq, Wk, Wv, Wo, WqT, WkT, WvT, WoT);
    proj_kernel<<<dim3(256, 3), 256, 0, stream>>>(Q, K, WqT, WkT, WvT, bq, bk, bv,
                                                  lengths, qb, kb, vT);
    attn_kernel<<<dim3(32, 64), 256, 0, stream>>>(qb, kb, vT, lengths, O1);
    ln0_kernel<<<dim3(2048), 256, 0, stream>>>(O1, g0, b0, Xb);
    out_kernel<<<dim3(256), 256, 0, stream>>>(Xb, WoT, bo, g1, b1, out);
}